// Round 4
// baseline (525.117 us; speedup 1.0000x reference)
//
#include <hip/hip_runtime.h>

// InternalInteraction: out[b,j,d] = sum_i [ relu((x_i*x_j)@W1^T + b1) @ W2^T + b2 ]
// Factored: hsum[b,j,h] = sum_i relu((x_i*x_j)@W1^T + b1); out = hsum@W2^T + 16*b2.
// B=2048, A=16, D=128, H=512. Storage fp32; MFMA in bf16.
//
// Round-7 structure (vs round-6):
//  - POST-MORTEM r6: stagger+setprio -4%. All scheduling levers null:
//    occupancy (r5), barriers (r3->r5), de-phasing (r6). Pipe demands are
//    ADDITIVE at this mix (MFMA 35 + LDS ~43 + VALU ~14 ~= 93 ~= wall).
//    Only remaining lever: cut total work.
//  - SYMMETRY CUT: pairs[i,j,d]=pairs[j,i,d] -> hidden activations for
//    shift delta=(i-j)&15 and 16-delta are the same values ROW-ROTATED.
//    Compute only delta=0..8 (9 tiles, not 16): GEMM1 MFMA -44%, A-frag
//    LDS reads -44%, pair-build -44%. For delta=1..7 each relu'd tile is
//    added twice: aligned (register add) and row-rotated via 16x
//    ds_bpermute (fixed cross-lane perm, same col -> conflict-free).
//    Same bf16 products, same relu values -> absmax unchanged.
//  - Reverted stagger & setprio (r6 regression); kept persistent bias4.
//  - LDS drops 78KB -> 48KB (ps now 9 tiles; hs still aliases ps).

#define BATCH 2048
#define AA 16
#define DD 128
#define HH 512

typedef __bf16 bf16;
typedef bf16  bf16x4 __attribute__((ext_vector_type(4)));
typedef bf16  bf16x8 __attribute__((ext_vector_type(8)));
typedef float f32x4  __attribute__((ext_vector_type(4)));

__device__ inline f32x4 splat4(float v) { f32x4 r = {v, v, v, v}; return r; }

// pull float from another lane: idx = source_lane * 4 (byte index)
__device__ inline float bperm_f32(int idx, float v) {
    return __int_as_float(__builtin_amdgcn_ds_bpermute(idx, __float_as_int(v)));
}

// ---- prologue: fp32 -> bf16 weight conversion into d_ws ----
// ws layout: [0, 65536)  = W1b (512x128 row-major bf16)
//            [65536, ..) = W2b (128x512 row-major bf16)
__global__ __launch_bounds__(256, 1)
void convert_weights(const float* __restrict__ W1,
                     const float* __restrict__ W2,
                     bf16* __restrict__ wsb)
{
    int t = blockIdx.x * 256 + threadIdx.x;      // 0..32767, 4 elems each
    f32x4 v = (t < 16384) ? *(const f32x4*)(W1 + 4 * t)
                          : *(const f32x4*)(W2 + 4 * (t - 16384));
    bf16x4 o;
    o[0] = (bf16)v[0]; o[1] = (bf16)v[1]; o[2] = (bf16)v[2]; o[3] = (bf16)v[3];
    *(bf16x4*)(wsb + 4 * t) = o;
}

// One block per batch. 512 threads = 8 waves; wave w owns H cols [w*64, w*64+64).
__global__ __launch_bounds__(512, 4)
void interact_kernel(const float* __restrict__ x,    // [B, A, D] fp32
                     const bf16*  __restrict__ W1b,  // [H, D] bf16 (from ws)
                     const float* __restrict__ b1,   // [H]
                     const bf16*  __restrict__ W2b,  // [D, H] bf16 (from ws)
                     const float* __restrict__ b2,   // [D]
                     float* __restrict__ out)        // [B, A, D] fp32
{
    // xs: x_b in f32, row stride 136 (544 B)
    __shared__ float xs[16][136];                               // 8704 B
    // ps: 9 shift-tiles [dlt][j][136] bf16; tile dlt row j = x_{(j+dlt)&15}*x_j.
    //     row stride 272 B -> A-frag b128 reads uniform over 8 bank-slots.
    // hs: GEMM2 staging [16][520] bf16 (16640 B) -- ALIASES ps (dead by then).
    __shared__ __align__(16) unsigned char smem_raw[9 * 16 * 136 * 2];  // 39168 B
    bf16 (*ps)[16][136] = reinterpret_cast<bf16(*)[16][136]>(smem_raw);
    bf16 (*hs)[520]     = reinterpret_cast<bf16(*)[520]>(smem_raw);

    const int b    = blockIdx.x;
    const int tid  = threadIdx.x;
    const int wave = tid >> 6;    // 0..7
    const int lane = tid & 63;
    const int quad = lane >> 4;   // 0..3
    const int col  = lane & 15;   // 0..15

    // build-phase coordinates: thread owns (jrow, dq..dq+4)
    const int jrow = tid >> 5;          // 0..15
    const int dq   = (tid & 31) * 4;    // 0..124

    // ---- stage x_b into LDS (f32); keep own 4-float slice in regs ----
    f32x4 xj;
    {
        const float* src = x + (size_t)b * (AA * DD) + jrow * DD + dq;
        xj = *(const f32x4*)src;
        *(f32x4*)(&xs[jrow][dq]) = xj;
    }

    // ---- W1 fragments, register-resident (4n x 4kk x 16B = 64 regs) ----
    // B-operand layout: lane holds B[k = quad*8+e + kk*32][n-col], row-major [N,K].
    bf16x8 w1f[4][4];
    f32x4  bias4[4];   // persistent C-seed: {b1[h]}x4 per n
#pragma unroll
    for (int n = 0; n < 4; ++n) {
        int h    = wave * 64 + n * 16 + col;
        bias4[n] = splat4(b1[h]);
#pragma unroll
        for (int kk = 0; kk < 4; ++kk)
            w1f[n][kk] = *(const bf16x8*)(W1b + h * DD + kk * 32 + quad * 8);
    }

    f32x4 hsum[4];
#pragma unroll
    for (int n = 0; n < 4; ++n) hsum[n] = splat4(0.f);

    __syncthreads();   // xs complete

    // ---- build 9 shift tiles: ps[dlt][j][d] = bf16(x_{(j+dlt)&15}[d]*x_j[d]) ----
#pragma unroll
    for (int dlt = 0; dlt < 9; ++dlt) {
        f32x4 xi = *(f32x4*)(&xs[(jrow + dlt) & 15][dq]);
        bf16x4 pr;
#pragma unroll
        for (int e = 0; e < 4; ++e) pr[e] = (bf16)(xj[e] * xi[e]);
        *(bf16x4*)(&ps[dlt][jrow][dq]) = pr;
    }
    __syncthreads();   // all tiles ready; no barriers until GEMM2 staging

    // ---- GEMM1 over 9 shift tiles ----
    // A-operand: lane holds A[row=col][k=quad*8+e (+32*kk)] from ps[dlt].
    // C/D layout: row j = quad*4+r, col = lane&15.
    // hsum[j] = sum_{dlt=0..15} relu-act(pair(j+dlt, j)); tiles dlt and
    // 16-dlt are row-rotated copies, so for dlt=1..7 add tile twice:
    //   aligned:  hsum[row] += v[row]
    //   rotated:  hsum[row] += v[(row - dlt) & 15]   (cross-lane bpermute)
    const int col4 = col << 2;   // byte offset of own col in source lane idx
    const int qrow = quad << 2;  // own row base

#pragma unroll
    for (int dlt = 0; dlt < 9; ++dlt) {
        bf16x8 af[4];
#pragma unroll
        for (int kk = 0; kk < 4; ++kk)
            af[kk] = *(bf16x8*)(&ps[dlt][col][kk * 32 + quad * 8]);

        f32x4 acc[4];
#pragma unroll
        for (int n = 0; n < 4; ++n)
            acc[n] = __builtin_amdgcn_mfma_f32_16x16x32_bf16(
                af[0], w1f[n][0], bias4[n], 0, 0, 0);
#pragma unroll
        for (int kk = 1; kk < 4; ++kk)
#pragma unroll
            for (int n = 0; n < 4; ++n)
                acc[n] = __builtin_amdgcn_mfma_f32_16x16x32_bf16(
                    af[kk], w1f[n][kk], acc[n], 0, 0, 0);

        // relu in place: acc now holds value_dlt[row]
#pragma unroll
        for (int n = 0; n < 4; ++n)
#pragma unroll
            for (int r = 0; r < 4; ++r)
                acc[n][r] = fmaxf(acc[n][r], 0.f);

        if (dlt >= 1 && dlt <= 7) {
            // source row for target row (qrow+r): srow = (qrow+r-dlt)&15
            // source lane = (srow>>2)*16 + col; source reg r_s = (r-dlt)&3
            int idx[4];
#pragma unroll
            for (int r = 0; r < 4; ++r) {
                int srow = (qrow + r - dlt) & 15;
                idx[r] = ((srow >> 2) << 6) | col4;
            }
#pragma unroll
            for (int n = 0; n < 4; ++n)
#pragma unroll
                for (int r = 0; r < 4; ++r)
                    hsum[n][r] += acc[n][r] +
                                  bperm_f32(idx[r], acc[n][(r - dlt) & 3]);
        } else {
            // dlt = 0 (diagonal) and dlt = 8 (self-paired shift): add once
#pragma unroll
            for (int n = 0; n < 4; ++n)
#pragma unroll
                for (int r = 0; r < 4; ++r)
                    hsum[n][r] += acc[n][r];
        }
    }

    __syncthreads();   // all ps reads done before hs overwrites the region

    // ---- hsum -> LDS (bf16) for GEMM2 A-operand re-layout ----
    // C/D layout: row j = quad*4+r, h-col = wave*64 + n*16 + col
#pragma unroll
    for (int n = 0; n < 4; ++n)
#pragma unroll
        for (int r = 0; r < 4; ++r)
            hs[quad * 4 + r][wave * 64 + n * 16 + col] = (bf16)hsum[n][r];

    __syncthreads();

    // ---- GEMM2: out[j,d] = hsum[j,:] @ W2^T + 16*b2 ----
    // M=16 (j), N=16 per wave (d = wave*16 + col), K=512 (h). W2b is [D,H].
    const int d = wave * 16 + col;
    f32x4 acc2 = splat4(16.f * b2[d]);

#pragma unroll
    for (int ks = 0; ks < 16; ++ks) {
        int h0 = ks * 32 + quad * 8;
        bf16x8 a2 = *(bf16x8*)(&hs[col][h0]);
        bf16x8 bw = *(const bf16x8*)(W2b + d * HH + h0);
        acc2 = __builtin_amdgcn_mfma_f32_16x16x32_bf16(a2, bw, acc2, 0, 0, 0);
    }

#pragma unroll
    for (int r = 0; r < 4; ++r) {
        int j = quad * 4 + r;
        out[(size_t)b * (AA * DD) + j * DD + d] = acc2[r];
    }
}

extern "C" void kernel_launch(void* const* d_in, const int* in_sizes, int n_in,
                              void* d_out, int out_size, void* d_ws, size_t ws_size,
                              hipStream_t stream)
{
    const float* x  = (const float*)d_in[0];  // [2048,16,128]
    const float* W1 = (const float*)d_in[1];  // [512,128]
    const float* b1 = (const float*)d_in[2];  // [512]
    const float* W2 = (const float*)d_in[3];  // [128,512]
    const float* b2 = (const float*)d_in[4];  // [128]
    float* out = (float*)d_out;

    bf16* wsb = (bf16*)d_ws;                  // 256 KB used
    convert_weights<<<128, 256, 0, stream>>>(W1, W2, wsb);

    const bf16* W1b = wsb;
    const bf16* W2b = wsb + (size_t)HH * DD;
    interact_kernel<<<BATCH, 512, 0, stream>>>(x, W1b, b1, W2b, b2, out);
}

// Round 5
// 146.689 us; speedup vs baseline: 3.5798x; 3.5798x over previous
//
#include <hip/hip_runtime.h>

// InternalInteraction: out[b,j,d] = sum_i [ relu((x_i*x_j)@W1^T + b1) @ W2^T + b2 ]
// Factored: hsum[b,j,h] = sum_i relu((x_i*x_j)@W1^T + b1); out = hsum@W2^T + 16*b2.
// B=2048, A=16, D=128, H=512. Storage fp32; MFMA in bf16.
//
// Round-8 structure (vs round-7):
//  - POST-MORTEM r7: symmetry cut regressed 5x from SCRATCH SPILL: full
//    unroll of the 9-tile loop (forced by static cross-reg rotation index
//    (r-dlt)&3) hoisted 36 af fragments -> WRITE_SIZE 16MB->1.4GB.
//  - FIX: SWAP MFMA OPERANDS. mfma(w1f, af) computes C^T: rows=h,
//    cols=j=lane&15. The row-rotation over j becomes a pure LANE rotation
//    (same register!), so the rotated add is one runtime-indexed
//    ds_bpermute per (n,r). No static indices -> loop stays unroll-1 ->
//    r5's proven no-spill register footprint.
//    Fragment symmetry makes the swap ~free: af and w1f LDS/global read
//    patterns are UNCHANGED; bias4 becomes an f32x4 load b1[h..h+3];
//    hs-write becomes 4x bf16x4 stores.
//  - Symmetry cut kept: 9 shift tiles instead of 16 -> GEMM1 MFMA -41%,
//    A-frag LDS reads -44%, build -44%. Tiles dlt and 16-dlt are equal
//    row-rotated: hsum[j] = sum_{d=0..8} v_d[j] + sum_{d=1..7} v_d[(j-d)&15].
//    Same bf16 products -> same relu values; only f32 add order changes.
//  - Keep from r5: unroll-1 GEMM1, 512 thr / 8 waves / 64 h per wave,
//    f32 xs staging, hs aliasing dead ps, no stagger/setprio (r6 null).

#define BATCH 2048
#define AA 16
#define DD 128
#define HH 512

typedef __bf16 bf16;
typedef bf16  bf16x4 __attribute__((ext_vector_type(4)));
typedef bf16  bf16x8 __attribute__((ext_vector_type(8)));
typedef float f32x4  __attribute__((ext_vector_type(4)));

__device__ inline f32x4 splat4(float v) { f32x4 r = {v, v, v, v}; return r; }

// pull float from another lane: idx = source_lane * 4 (byte index)
__device__ inline float bperm_f32(int idx, float v) {
    return __int_as_float(__builtin_amdgcn_ds_bpermute(idx, __float_as_int(v)));
}

// ---- prologue: fp32 -> bf16 weight conversion into d_ws ----
// ws layout: [0, 65536)  = W1b (512x128 row-major bf16)
//            [65536, ..) = W2b (128x512 row-major bf16)
__global__ __launch_bounds__(256, 1)
void convert_weights(const float* __restrict__ W1,
                     const float* __restrict__ W2,
                     bf16* __restrict__ wsb)
{
    int t = blockIdx.x * 256 + threadIdx.x;      // 0..32767, 4 elems each
    f32x4 v = (t < 16384) ? *(const f32x4*)(W1 + 4 * t)
                          : *(const f32x4*)(W2 + 4 * (t - 16384));
    bf16x4 o;
    o[0] = (bf16)v[0]; o[1] = (bf16)v[1]; o[2] = (bf16)v[2]; o[3] = (bf16)v[3];
    *(bf16x4*)(wsb + 4 * t) = o;
}

// One block per batch. 512 threads = 8 waves; wave w owns H cols [w*64, w*64+64).
__global__ __launch_bounds__(512, 4)
void interact_kernel(const float* __restrict__ x,    // [B, A, D] fp32
                     const bf16*  __restrict__ W1b,  // [H, D] bf16 (from ws)
                     const float* __restrict__ b1,   // [H]
                     const bf16*  __restrict__ W2b,  // [D, H] bf16 (from ws)
                     const float* __restrict__ b2,   // [D]
                     float* __restrict__ out)        // [B, A, D] fp32
{
    // xs: x_b in f32, row stride 136 (544 B)
    __shared__ float xs[16][136];                               // 8704 B
    // ps: 9 shift-tiles [dlt][j][136] bf16; tile dlt row j = x_{(j+dlt)&15}*x_j.
    //     row stride 272 B -> frag b128 reads uniform over 8 bank-slots.
    // hs: GEMM2 staging [16][520] bf16 (16640 B) -- ALIASES ps (dead by then).
    __shared__ __align__(16) unsigned char smem_raw[9 * 16 * 136 * 2];  // 39168 B
    bf16 (*ps)[16][136] = reinterpret_cast<bf16(*)[16][136]>(smem_raw);
    bf16 (*hs)[520]     = reinterpret_cast<bf16(*)[520]>(smem_raw);

    const int b    = blockIdx.x;
    const int tid  = threadIdx.x;
    const int wave = tid >> 6;    // 0..7
    const int lane = tid & 63;
    const int quad = lane >> 4;   // 0..3
    const int col  = lane & 15;   // 0..15

    // build-phase coordinates: thread owns (jrow, dq..dq+4)
    const int jrow = tid >> 5;          // 0..15
    const int dq   = (tid & 31) * 4;    // 0..124

    // ---- stage x_b into LDS (f32); keep own 4-float slice in regs ----
    f32x4 xj;
    {
        const float* src = x + (size_t)b * (AA * DD) + jrow * DD + dq;
        xj = *(const f32x4*)src;
        *(f32x4*)(&xs[jrow][dq]) = xj;
    }

    // ---- W1 fragments, register-resident (4n x 4kk x 16B = 64 regs) ----
    // Used as MFMA arg0 (A-operand): lane holds W1b[h = n*16+col][k-slice].
    bf16x8 w1f[4][4];
    f32x4  bias4[4];   // C-seed: b1[h0 + quad*4 + r] per reg r (C rows = h now)
#pragma unroll
    for (int n = 0; n < 4; ++n) {
        int h    = wave * 64 + n * 16 + col;
        bias4[n] = *(const f32x4*)(b1 + wave * 64 + n * 16 + quad * 4);
#pragma unroll
        for (int kk = 0; kk < 4; ++kk)
            w1f[n][kk] = *(const bf16x8*)(W1b + h * DD + kk * 32 + quad * 8);
    }

    f32x4 hsum[4];
#pragma unroll
    for (int n = 0; n < 4; ++n) hsum[n] = splat4(0.f);

    __syncthreads();   // xs complete

    // ---- build 9 shift tiles: ps[dlt][j][d] = bf16(x_{(j+dlt)&15}[d]*x_j[d]) ----
#pragma unroll
    for (int dlt = 0; dlt < 9; ++dlt) {
        f32x4 xi = *(f32x4*)(&xs[(jrow + dlt) & 15][dq]);
        bf16x4 pr;
#pragma unroll
        for (int e = 0; e < 4; ++e) pr[e] = (bf16)(xj[e] * xi[e]);
        *(bf16x4*)(&ps[dlt][jrow][dq]) = pr;
    }
    __syncthreads();   // all tiles ready; no barriers until GEMM2 staging

    // ---- GEMM1 over 9 shift tiles (SWAPPED operands: C rows=h, cols=j) ----
    // arg0 = w1f (A rows = h-sub = col), arg1 = af (B cols = j = col).
    // C/D: lane(q,c) holds v[h = base + n*16 + q*4 + r][j = c].
    // hsum[j] = sum_{d=0..8} v_d[j] + sum_{d=1..7} v_d[(j-d)&15]; the second
    // term is a pure lane-rotation within the 16-lane col group -> one
    // runtime-indexed ds_bpermute per (n,r), same register. unroll 1!
#pragma unroll 1
    for (int dlt = 0; dlt < 9; ++dlt) {
        bf16x8 af[4];
#pragma unroll
        for (int kk = 0; kk < 4; ++kk)
            af[kk] = *(bf16x8*)(&ps[dlt][col][kk * 32 + quad * 8]);

        f32x4 v[4];
#pragma unroll
        for (int n = 0; n < 4; ++n)
            v[n] = __builtin_amdgcn_mfma_f32_16x16x32_bf16(
                w1f[n][0], af[0], bias4[n], 0, 0, 0);
#pragma unroll
        for (int kk = 1; kk < 4; ++kk)
#pragma unroll
            for (int n = 0; n < 4; ++n)
                v[n] = __builtin_amdgcn_mfma_f32_16x16x32_bf16(
                    w1f[n][kk], af[kk], v[n], 0, 0, 0);

        // relu in place
#pragma unroll
        for (int n = 0; n < 4; ++n)
#pragma unroll
            for (int r = 0; r < 4; ++r)
                v[n][r] = fmaxf(v[n][r], 0.f);

        // aligned add
#pragma unroll
        for (int n = 0; n < 4; ++n)
#pragma unroll
            for (int r = 0; r < 4; ++r)
                hsum[n][r] += v[n][r];

        // rotated add (tile 16-dlt): lane j takes lane (j-dlt)&15, same quad
        if (dlt >= 1 && dlt <= 7) {
            const int idx = ((quad << 4) | ((col - dlt) & 15)) << 2;
#pragma unroll
            for (int n = 0; n < 4; ++n)
#pragma unroll
                for (int r = 0; r < 4; ++r)
                    hsum[n][r] += bperm_f32(idx, v[n][r]);
        }
    }

    __syncthreads();   // all ps reads done before hs overwrites the region

    // ---- hsum -> LDS (bf16) for GEMM2 A-operand re-layout ----
    // Transposed C layout: lane(q,c) holds hsum[j=c][h = w*64+n*16+q*4+r]
    // -> contiguous in h: one bf16x4 store per n.
#pragma unroll
    for (int n = 0; n < 4; ++n) {
        bf16x4 o;
#pragma unroll
        for (int r = 0; r < 4; ++r) o[r] = (bf16)hsum[n][r];
        *(bf16x4*)(&hs[col][wave * 64 + n * 16 + quad * 4]) = o;
    }

    __syncthreads();

    // ---- GEMM2: out[j,d] = hsum[j,:] @ W2^T + 16*b2 ----
    // M=16 (j), N=16 per wave (d = wave*16 + col), K=512 (h). W2b is [D,H].
    const int d = wave * 16 + col;
    f32x4 acc2 = splat4(16.f * b2[d]);

#pragma unroll
    for (int ks = 0; ks < 16; ++ks) {
        int h0 = ks * 32 + quad * 8;
        bf16x8 a2 = *(bf16x8*)(&hs[col][h0]);
        bf16x8 bw = *(const bf16x8*)(W2b + d * HH + h0);
        acc2 = __builtin_amdgcn_mfma_f32_16x16x32_bf16(a2, bw, acc2, 0, 0, 0);
    }

#pragma unroll
    for (int r = 0; r < 4; ++r) {
        int j = quad * 4 + r;
        out[(size_t)b * (AA * DD) + j * DD + d] = acc2[r];
    }
}

extern "C" void kernel_launch(void* const* d_in, const int* in_sizes, int n_in,
                              void* d_out, int out_size, void* d_ws, size_t ws_size,
                              hipStream_t stream)
{
    const float* x  = (const float*)d_in[0];  // [2048,16,128]
    const float* W1 = (const float*)d_in[1];  // [512,128]
    const float* b1 = (const float*)d_in[2];  // [512]
    const float* W2 = (const float*)d_in[3];  // [128,512]
    const float* b2 = (const float*)d_in[4];  // [128]
    float* out = (float*)d_out;

    bf16* wsb = (bf16*)d_ws;                  // 256 KB used
    convert_weights<<<128, 256, 0, stream>>>(W1, W2, wsb);

    const bf16* W1b = wsb;
    const bf16* W2b = wsb + (size_t)HH * DD;
    interact_kernel<<<BATCH, 512, 0, stream>>>(x, W1b, b1, W2b, b2, out);
}